// Round 1
// 126.277 us; speedup vs baseline: 1.1935x; 1.1935x over previous
//
#include <hip/hip_runtime.h>
#include <hip/hip_bf16.h>

// Problem constants (from reference)
constexpr int N_SAMPLES = 512;
constexpr int J_GENES   = 20000;
constexpr int P_COV     = 8;
constexpr int DIM       = J_GENES - 1;   // pivot=True: last logit column is 0
constexpr int BLOCK     = 256;           // prep / fallback block
constexpr int TPB       = 1024;          // fused kernel threads (16 waves)
constexpr int SWEEP_G   = TPB * 4;       // 4096 genes per sweep (float4/thread)
constexpr int SWEEPS    = (J_GENES + SWEEP_G - 1) / SWEEP_G;   // 5
constexpr int TABLE_N   = 1024;          // lgamma(y+1) table, y in [0,1000]

// ---------------------------------------------------------------------------
// ws layout (floats):
//   rw      [J]       r = 1/softplus(phi)
//   logrw   [J]       log(r)
//   lgrw    [J]       lgamma(r)
//   muP     [J]       mu padded with 0 at j=DIM  (pivot logit = 0 falls out)
//   betaP   [P*J]     beta repacked [p][J], padded, float4-alignable
//   lgyt    [1024]    lgamma(k+1) table
constexpr size_t WS_RW    = 0;
constexpr size_t WS_LOGRW = WS_RW    + J_GENES;
constexpr size_t WS_LGRW  = WS_LOGRW + J_GENES;
constexpr size_t WS_MUP   = WS_LGRW  + J_GENES;
constexpr size_t WS_BETAP = WS_MUP   + J_GENES;
constexpr size_t WS_LGYT  = WS_BETAP + (size_t)P_COV * J_GENES;
constexpr size_t WS_TOTAL = WS_LGYT  + TABLE_N;   // floats

__device__ inline float wave_reduce_sum(float v) {
#pragma unroll
    for (int off = 32; off > 0; off >>= 1)
        v += __shfl_down(v, off, 64);
    return v;
}

// Stirling lgamma for z > 0.2. Shift threshold 2 (was 8): only y<=1 lanes
// diverge (~0.2% of lanes vs 0.8%), and 3-term Stirling at z>=2.25 has abs
// error <= ~3e-6 — far inside the 2% absmax threshold.
__device__ inline float lgamma_pos(float z) {
    float corr = 0.0f;
    if (z < 2.0f) {
        corr = -__logf(z * (z + 1.0f));
        z += 2.0f;
    }
    float lz  = __logf(z);
    float rz  = __builtin_amdgcn_rcpf(z);
    float rz2 = rz * rz;
    // 1/(12z) - 1/(360 z^3) + 1/(1260 z^5)
    float ser = rz * fmaf(rz2, fmaf(rz2, 7.9365079365e-4f, -2.7777777778e-3f),
                          8.3333333333e-2f);
    return fmaf(z - 0.5f, lz, 0.91893853320467274f - z + ser + corr);
}

// ---------------------------------------------------------------------------
__global__ __launch_bounds__(BLOCK) void prep_kernel(
    const float* __restrict__ mu, const float* __restrict__ beta,
    const float* __restrict__ phi, float* __restrict__ ws,
    float* __restrict__ out) {
    int j = blockIdx.x * blockDim.x + threadIdx.x;
    if (j == 0) out[0] = 0.0f;   // fused blocks atomicAdd into out
    if (j < TABLE_N) ws[WS_LGYT + j] = lgammaf((float)j + 1.0f);
    if (j < J_GENES) {
        float ph = phi[j];
        float sp = (ph > 20.0f) ? ph : log1pf(__expf(ph));  // softplus
        float r  = 1.0f / sp;
        ws[WS_RW    + j] = r;
        ws[WS_LOGRW + j] = -__logf(sp);
        ws[WS_LGRW  + j] = lgammaf(r);
        ws[WS_MUP   + j] = (j < DIM) ? mu[j] : 0.0f;
#pragma unroll
        for (int p = 0; p < P_COV; ++p)
            ws[WS_BETAP + (size_t)p * J_GENES + j] =
                (j < DIM) ? beta[p * DIM + j] : 0.0f;
    }
}

// ---------------------------------------------------------------------------
// Fused kernel: one block per sample row.
// Phase A: stream Y + logits, keep y and exp(logit) in REGISTERS, accumulate
//          s = sum(Y), E = sum(exp(logit)).
// Block reduce -> c = s/E (mean = c * elog; log(mean) computed directly, so
// the second exp of the old 2-pass structure disappears).
// Phase B: NB log-lik from registers + per-gene tables (L2-resident).
// Per-block partial -> atomicAdd(out). Y and betaP each read ONCE.
__device__ inline float nb_term(float y, float el, float r, float logr,
                                float lgr, float c,
                                const float* __restrict__ tbl) {
    float mean = c * el;
    float lm   = __logf(mean);           // = log(s) + logit - lse
    float lrm  = __logf(r + mean);
    int   yi   = (int)(y + 0.5f);
    float lgy1 = (yi < TABLE_N) ? tbl[yi] : lgamma_pos(y + 1.0f);
    float lgyr = lgamma_pos(y + r);
    // lgamma(y+r) - lgamma(r) - lgamma(y+1) + r*(logr - lrm) + y*(logmean - lrm)
    return lgyr - lgr - lgy1 + fmaf(r, logr - lrm, y * (lm - lrm));
}

__global__ __launch_bounds__(TPB) void fused_kernel(
    const float* __restrict__ X, const float* __restrict__ Y,
    const float* __restrict__ ws_c, float* __restrict__ out) {
    const int n = blockIdx.x;
    const int t = threadIdx.x;

    __shared__ __align__(16) float tbl[TABLE_N];
    __shared__ float rs[TPB / 64], re[TPB / 64];
    __shared__ float sh_c;

    tbl[t] = ws_c[WS_LGYT + t];          // 1024 threads, one entry each

    float x[P_COV];
#pragma unroll
    for (int p = 0; p < P_COV; ++p) x[p] = X[n * P_COV + p];

    const float* __restrict__ yrow = Y + (size_t)n * J_GENES;

    // Phase A -------------------------------------------------------------
    float4 y4[SWEEPS], e4[SWEEPS];       // 40 VGPRs of row state
    float s_acc = 0.0f, e_acc = 0.0f;
#pragma unroll
    for (int w = 0; w < SWEEPS; ++w) {
        const int j = w * SWEEP_G + t * 4;
        if (j < J_GENES) {               // 20000 % 4 == 0: whole quads valid
            float4 yy = *(const float4*)(yrow + j);
            float4 lg = *(const float4*)(ws_c + WS_MUP + j);
#pragma unroll
            for (int p = 0; p < P_COV; ++p) {
                float4 b = *(const float4*)(ws_c + WS_BETAP + (size_t)p * J_GENES + j);
                lg.x = fmaf(x[p], b.x, lg.x);
                lg.y = fmaf(x[p], b.y, lg.y);
                lg.z = fmaf(x[p], b.z, lg.z);
                lg.w = fmaf(x[p], b.w, lg.w);
            }
            float4 ee = make_float4(__expf(lg.x), __expf(lg.y),
                                    __expf(lg.z), __expf(lg.w));
            y4[w] = yy;
            e4[w] = ee;
            s_acc += (yy.x + yy.y) + (yy.z + yy.w);
            e_acc += (ee.x + ee.y) + (ee.z + ee.w);
        } else {
            y4[w] = make_float4(0.f, 0.f, 0.f, 0.f);
            e4[w] = make_float4(0.f, 0.f, 0.f, 0.f);
        }
    }

    // Block reduction for s and E -----------------------------------------
    float vs = wave_reduce_sum(s_acc);
    float ve = wave_reduce_sum(e_acc);
    if ((t & 63) == 0) { rs[t >> 6] = vs; re[t >> 6] = ve; }
    __syncthreads();
    if (t == 0) {
        float s = 0.0f, E = 0.0f;
#pragma unroll
        for (int i = 0; i < TPB / 64; ++i) { s += rs[i]; E += re[i]; }
        sh_c = s / E;                    // mean = (s/E) * exp(logit)
    }
    __syncthreads();
    const float c = sh_c;

    // Phase B -------------------------------------------------------------
    float acc = 0.0f;
#pragma unroll
    for (int w = 0; w < SWEEPS; ++w) {
        const int j = w * SWEEP_G + t * 4;
        if (j < J_GENES) {
            float4 r4  = *(const float4*)(ws_c + WS_RW    + j);
            float4 lr4 = *(const float4*)(ws_c + WS_LOGRW + j);
            float4 lg4 = *(const float4*)(ws_c + WS_LGRW  + j);
            acc += nb_term(y4[w].x, e4[w].x, r4.x, lr4.x, lg4.x, c, tbl);
            acc += nb_term(y4[w].y, e4[w].y, r4.y, lr4.y, lg4.y, c, tbl);
            acc += nb_term(y4[w].z, e4[w].z, r4.z, lr4.z, lg4.z, c, tbl);
            acc += nb_term(y4[w].w, e4[w].w, r4.w, lr4.w, lg4.w, c, tbl);
        }
    }

    float v = wave_reduce_sum(acc);
    if ((t & 63) == 0) rs[t >> 6] = v;   // reuse rs
    __syncthreads();
    if (t == 0) {
        float tot = 0.0f;
#pragma unroll
        for (int i = 0; i < TPB / 64; ++i) tot += rs[i];
        atomicAdd(out, tot);
    }
}

// ---------------------------------------------------------------------------
// Fallback (ws too small): round-1 monolithic kernel, known-correct.
__global__ __launch_bounds__(BLOCK) void nb_mono(
    const float* __restrict__ mu, const float* __restrict__ beta,
    const float* __restrict__ phi, const float* __restrict__ X,
    const float* __restrict__ Y, float* __restrict__ out) {
    const int n = blockIdx.x;
    const int t = threadIdx.x;
    __shared__ float red[4];
    __shared__ float sh_s, sh_lse, sh_logs;
    float x[P_COV];
#pragma unroll
    for (int p = 0; p < P_COV; ++p) x[p] = X[n * P_COV + p];
    const float* yrow = Y + (size_t)n * J_GENES;
    float s_acc = 0.0f, e_acc = 0.0f;
    for (int j = t; j < J_GENES; j += BLOCK) {
        float logit = 0.0f;
        if (j < DIM) {
            logit = mu[j];
#pragma unroll
            for (int p = 0; p < P_COV; ++p)
                logit = fmaf(x[p], beta[p * DIM + j], logit);
        }
        s_acc += yrow[j];
        e_acc += __expf(logit);
    }
    float v = wave_reduce_sum(s_acc);
    if ((t & 63) == 0) red[t >> 6] = v;
    __syncthreads();
    if (t == 0) { float st = red[0]+red[1]+red[2]+red[3]; sh_s = st; sh_logs = __logf(st); }
    __syncthreads();
    v = wave_reduce_sum(e_acc);
    if ((t & 63) == 0) red[t >> 6] = v;
    __syncthreads();
    if (t == 0) sh_lse = __logf(red[0]+red[1]+red[2]+red[3]);
    __syncthreads();
    const float s = sh_s, logs = sh_logs, lse = sh_lse;
    float acc = 0.0f;
    for (int j = t; j < J_GENES; j += BLOCK) {
        float logit = 0.0f;
        if (j < DIM) {
            logit = mu[j];
#pragma unroll
            for (int p = 0; p < P_COV; ++p)
                logit = fmaf(x[p], beta[p * DIM + j], logit);
        }
        float ph = phi[j];
        float sp = (ph > 20.0f) ? ph : log1pf(__expf(ph));
        float r  = 1.0f / sp;
        float y  = yrow[j];
        float lp = logit - lse;
        float mean = s * __expf(lp);
        float lrm  = __logf(r + mean);
        acc += lgamma_pos(y + r) - lgamma_pos(r) - lgamma_pos(y + 1.0f)
             + fmaf(r, -__logf(sp) - lrm, y * ((logs + lp) - lrm));
    }
    v = wave_reduce_sum(acc);
    if ((t & 63) == 0) red[t >> 6] = v;
    __syncthreads();
    if (t == 0) atomicAdd(out, (red[0]+red[1])+(red[2]+red[3]));
}

__global__ void zero_out_kernel(float* __restrict__ out) { out[0] = 0.0f; }

// ---------------------------------------------------------------------------
extern "C" void kernel_launch(void* const* d_in, const int* in_sizes, int n_in,
                              void* d_out, int out_size, void* d_ws, size_t ws_size,
                              hipStream_t stream) {
    const float* mu   = (const float*)d_in[0];  // [DIM]
    const float* beta = (const float*)d_in[1];  // [P*DIM]
    const float* phi  = (const float*)d_in[2];  // [J]
    const float* X    = (const float*)d_in[3];  // [N,P]
    const float* Y    = (const float*)d_in[4];  // [N,J]
    float* out = (float*)d_out;
    float* ws  = (float*)d_ws;

    if (ws_size >= WS_TOTAL * sizeof(float)) {
        prep_kernel<<<(J_GENES + BLOCK - 1) / BLOCK, BLOCK, 0, stream>>>(
            mu, beta, phi, ws, out);
        fused_kernel<<<N_SAMPLES, TPB, 0, stream>>>(X, Y, ws, out);
    } else {
        zero_out_kernel<<<1, 1, 0, stream>>>(out);
        nb_mono<<<N_SAMPLES, BLOCK, 0, stream>>>(mu, beta, phi, X, Y, out);
    }
}

// Round 2
// 123.587 us; speedup vs baseline: 1.2195x; 1.0218x over previous
//
#include <hip/hip_runtime.h>

// Problem constants (from reference)
constexpr int N_SAMPLES = 512;
constexpr int J_GENES   = 20000;
constexpr int P_COV     = 8;
constexpr int DIM       = J_GENES - 1;   // pivot=True: last logit column is 0
constexpr int BLOCK     = 256;
constexpr int TABLE_N   = 1024;          // lgamma(y+1) table, y in [0,1000]

// Gene-tiled decomposition: block owns CHUNK_G genes (4/thread), loops ROWS rows.
constexpr int CHUNK_G   = 1024;
constexpr int G_CHUNKS  = (J_GENES + CHUNK_G - 1) / CHUNK_G;   // 20
constexpr int ROWS      = 8;
constexpr int RGROUPS   = N_SAMPLES / ROWS;                    // 64

// ---------------------------------------------------------------------------
// ws layout (floats):
//   rw      [J]       r = 1/softplus(phi)
//   kw      [J]       K = r*log(r) - lgamma(r)        (folded per-gene const)
//   muP     [J]       mu padded with 0 at j=DIM
//   betaP   [P*J]     beta repacked [p][J], padded
//   lgyt    [1024]    lgamma(k+1) table
//   sAcc    [512]     per-row sum(Y)      (atomicAdd targets)
//   eAcc    [512]     per-row sum(exp(logit))
constexpr size_t WS_RW    = 0;
constexpr size_t WS_K     = WS_RW    + J_GENES;
constexpr size_t WS_MUP   = WS_K     + J_GENES;
constexpr size_t WS_BETAP = WS_MUP   + J_GENES;
constexpr size_t WS_LGYT  = WS_BETAP + (size_t)P_COV * J_GENES;
constexpr size_t WS_SACC  = WS_LGYT  + TABLE_N;
constexpr size_t WS_EACC  = WS_SACC  + N_SAMPLES;
constexpr size_t WS_TOTAL = WS_EACC  + N_SAMPLES;   // floats

__device__ inline float wave_reduce_sum(float v) {
#pragma unroll
    for (int off = 32; off > 0; off >>= 1)
        v += __shfl_down(v, off, 64);
    return v;
}

// Stirling lgamma for z > 0.2; shift-by-2 for z<2 (abs err <= ~3e-6).
__device__ inline float lgamma_pos(float z) {
    float corr = 0.0f;
    if (z < 2.0f) {
        corr = -__logf(z * (z + 1.0f));
        z += 2.0f;
    }
    float lz  = __logf(z);
    float rz  = __builtin_amdgcn_rcpf(z);
    float rz2 = rz * rz;
    // 1/(12z) - 1/(360 z^3) + 1/(1260 z^5)
    float ser = rz * fmaf(rz2, fmaf(rz2, 7.9365079365e-4f, -2.7777777778e-3f),
                          8.3333333333e-2f);
    return fmaf(z - 0.5f, lz, 0.91893853320467274f - z + ser + corr);
}

// ---------------------------------------------------------------------------
__global__ __launch_bounds__(BLOCK) void prep_kernel(
    const float* __restrict__ mu, const float* __restrict__ beta,
    const float* __restrict__ phi, float* __restrict__ ws,
    float* __restrict__ out) {
    int j = blockIdx.x * blockDim.x + threadIdx.x;
    if (j == 0) out[0] = 0.0f;
    if (j < N_SAMPLES) { ws[WS_SACC + j] = 0.0f; ws[WS_EACC + j] = 0.0f; }
    if (j < TABLE_N)   ws[WS_LGYT + j] = lgammaf((float)j + 1.0f);
    if (j < J_GENES) {
        float ph = phi[j];
        float sp = (ph > 20.0f) ? ph : log1pf(__expf(ph));  // softplus
        float r  = 1.0f / sp;
        float lr = -__logf(sp);                              // log(r)
        ws[WS_RW  + j] = r;
        ws[WS_K   + j] = fmaf(r, lr, -lgammaf(r));           // r*log r - lgamma(r)
        ws[WS_MUP + j] = (j < DIM) ? mu[j] : 0.0f;
#pragma unroll
        for (int p = 0; p < P_COV; ++p)
            ws[WS_BETAP + (size_t)p * J_GENES + j] =
                (j < DIM) ? beta[p * DIM + j] : 0.0f;
    }
}

// ---------------------------------------------------------------------------
// Kernel 1: per-row s = sum(Y), E = sum(exp(logit)).
// Gene-tiled: betaP/muP quads live in registers across the 8-row loop.
__global__ __launch_bounds__(BLOCK, 4) void sums_kernel(
    const float* __restrict__ X, const float* __restrict__ Y,
    const float* __restrict__ ws_c, float* __restrict__ ws) {
    const int t  = threadIdx.x;
    const int j0 = blockIdx.x * CHUNK_G + t * 4;
    const bool valid = j0 < J_GENES;        // 20000 % 4 == 0: whole quads

    float4 mu4 = make_float4(0.f, 0.f, 0.f, 0.f);
    float4 bp[P_COV];
#pragma unroll
    for (int p = 0; p < P_COV; ++p) bp[p] = make_float4(0.f, 0.f, 0.f, 0.f);
    if (valid) {
        mu4 = *(const float4*)(ws_c + WS_MUP + j0);
#pragma unroll
        for (int p = 0; p < P_COV; ++p)
            bp[p] = *(const float4*)(ws_c + WS_BETAP + (size_t)p * J_GENES + j0);
    }

    __shared__ float redS[BLOCK / 64], redE[BLOCK / 64];

    for (int rr = 0; rr < ROWS; ++rr) {
        const int n = blockIdx.y * ROWS + rr;
        float x[P_COV];
#pragma unroll
        for (int p = 0; p < P_COV; ++p) x[p] = X[n * P_COV + p];

        float sa = 0.0f, ea = 0.0f;
        if (valid) {
            float4 y4 = *(const float4*)(Y + (size_t)n * J_GENES + j0);
            float4 lg = mu4;
#pragma unroll
            for (int p = 0; p < P_COV; ++p) {
                lg.x = fmaf(x[p], bp[p].x, lg.x);
                lg.y = fmaf(x[p], bp[p].y, lg.y);
                lg.z = fmaf(x[p], bp[p].z, lg.z);
                lg.w = fmaf(x[p], bp[p].w, lg.w);
            }
            sa = (y4.x + y4.y) + (y4.z + y4.w);
            ea = (__expf(lg.x) + __expf(lg.y)) + (__expf(lg.z) + __expf(lg.w));
        }
        float vs = wave_reduce_sum(sa);
        float ve = wave_reduce_sum(ea);
        if ((t & 63) == 0) { redS[t >> 6] = vs; redE[t >> 6] = ve; }
        __syncthreads();
        if (t == 0) {
            atomicAdd(&ws[WS_SACC + n], (redS[0] + redS[1]) + (redS[2] + redS[3]));
            atomicAdd(&ws[WS_EACC + n], (redE[0] + redE[1]) + (redE[2] + redE[3]));
        }
        __syncthreads();
    }
}

// ---------------------------------------------------------------------------
// Kernel 2: NB log-likelihood.
// term_j = lgamma(y+r) - lgamma(y+1) + K_j - (y+r)*log(r+mean) + y*(log c + logit)
// with mean = c*exp(logit), c = s/E  (so log(mean) needs no log).
__device__ inline float nb_elem(float y, float lg, float r, float K,
                                float c, float logc,
                                const float* __restrict__ tbl) {
    float el   = __expf(lg);
    float mean = c * el;
    float z    = y + r;
    float lrm  = __logf(r + mean);
    float lgyr = lgamma_pos(z);
    float lgy1 = tbl[(int)(y + 0.5f)];
    return (lgyr - lgy1 + K) + fmaf(-z, lrm, y * (logc + lg));
}

__global__ __launch_bounds__(BLOCK, 4) void nb_kernel(
    const float* __restrict__ X, const float* __restrict__ Y,
    const float* __restrict__ ws_c, float* __restrict__ out) {
    const int t  = threadIdx.x;
    const int j0 = blockIdx.x * CHUNK_G + t * 4;
    const bool valid = j0 < J_GENES;

    __shared__ __align__(16) float tbl[TABLE_N];
    *(float4*)&tbl[t * 4] = *(const float4*)(ws_c + WS_LGYT + t * 4);

    float4 mu4 = make_float4(0.f, 0.f, 0.f, 0.f);
    float4 r4  = make_float4(1.f, 1.f, 1.f, 1.f);
    float4 K4  = make_float4(0.f, 0.f, 0.f, 0.f);
    float4 bp[P_COV];
#pragma unroll
    for (int p = 0; p < P_COV; ++p) bp[p] = make_float4(0.f, 0.f, 0.f, 0.f);
    if (valid) {
        mu4 = *(const float4*)(ws_c + WS_MUP + j0);
        r4  = *(const float4*)(ws_c + WS_RW  + j0);
        K4  = *(const float4*)(ws_c + WS_K   + j0);
#pragma unroll
        for (int p = 0; p < P_COV; ++p)
            bp[p] = *(const float4*)(ws_c + WS_BETAP + (size_t)p * J_GENES + j0);
    }
    __syncthreads();   // tbl ready

    float acc = 0.0f;
    for (int rr = 0; rr < ROWS; ++rr) {
        const int n = blockIdx.y * ROWS + rr;
        const float s = ws_c[WS_SACC + n];
        const float E = ws_c[WS_EACC + n];
        const float c = s / E;
        const float logc = __logf(c);

        float x[P_COV];
#pragma unroll
        for (int p = 0; p < P_COV; ++p) x[p] = X[n * P_COV + p];

        if (valid) {
            float4 y4 = *(const float4*)(Y + (size_t)n * J_GENES + j0);
            float4 lg = mu4;
#pragma unroll
            for (int p = 0; p < P_COV; ++p) {
                lg.x = fmaf(x[p], bp[p].x, lg.x);
                lg.y = fmaf(x[p], bp[p].y, lg.y);
                lg.z = fmaf(x[p], bp[p].z, lg.z);
                lg.w = fmaf(x[p], bp[p].w, lg.w);
            }
            acc += nb_elem(y4.x, lg.x, r4.x, K4.x, c, logc, tbl);
            acc += nb_elem(y4.y, lg.y, r4.y, K4.y, c, logc, tbl);
            acc += nb_elem(y4.z, lg.z, r4.z, K4.z, c, logc, tbl);
            acc += nb_elem(y4.w, lg.w, r4.w, K4.w, c, logc, tbl);
        }
    }

    float v = wave_reduce_sum(acc);
    __shared__ float red[BLOCK / 64];
    if ((t & 63) == 0) red[t >> 6] = v;
    __syncthreads();
    if (t == 0)
        atomicAdd(out, (red[0] + red[1]) + (red[2] + red[3]));
}

// ---------------------------------------------------------------------------
// Fallback (ws too small): round-1 monolithic kernel, known-correct.
__global__ __launch_bounds__(BLOCK) void nb_mono(
    const float* __restrict__ mu, const float* __restrict__ beta,
    const float* __restrict__ phi, const float* __restrict__ X,
    const float* __restrict__ Y, float* __restrict__ out) {
    const int n = blockIdx.x;
    const int t = threadIdx.x;
    __shared__ float red[4];
    __shared__ float sh_s, sh_lse, sh_logs;
    float x[P_COV];
#pragma unroll
    for (int p = 0; p < P_COV; ++p) x[p] = X[n * P_COV + p];
    const float* yrow = Y + (size_t)n * J_GENES;
    float s_acc = 0.0f, e_acc = 0.0f;
    for (int j = t; j < J_GENES; j += BLOCK) {
        float logit = 0.0f;
        if (j < DIM) {
            logit = mu[j];
#pragma unroll
            for (int p = 0; p < P_COV; ++p)
                logit = fmaf(x[p], beta[p * DIM + j], logit);
        }
        s_acc += yrow[j];
        e_acc += __expf(logit);
    }
    float v = wave_reduce_sum(s_acc);
    if ((t & 63) == 0) red[t >> 6] = v;
    __syncthreads();
    if (t == 0) { float st = red[0]+red[1]+red[2]+red[3]; sh_s = st; sh_logs = __logf(st); }
    __syncthreads();
    v = wave_reduce_sum(e_acc);
    if ((t & 63) == 0) red[t >> 6] = v;
    __syncthreads();
    if (t == 0) sh_lse = __logf(red[0]+red[1]+red[2]+red[3]);
    __syncthreads();
    const float s = sh_s, logs = sh_logs, lse = sh_lse;
    float acc = 0.0f;
    for (int j = t; j < J_GENES; j += BLOCK) {
        float logit = 0.0f;
        if (j < DIM) {
            logit = mu[j];
#pragma unroll
            for (int p = 0; p < P_COV; ++p)
                logit = fmaf(x[p], beta[p * DIM + j], logit);
        }
        float ph = phi[j];
        float sp = (ph > 20.0f) ? ph : log1pf(__expf(ph));
        float r  = 1.0f / sp;
        float y  = yrow[j];
        float lp = logit - lse;
        float mean = s * __expf(lp);
        float lrm  = __logf(r + mean);
        acc += lgamma_pos(y + r) - lgamma_pos(r) - lgamma_pos(y + 1.0f)
             + fmaf(r, -__logf(sp) - lrm, y * ((logs + lp) - lrm));
    }
    v = wave_reduce_sum(acc);
    if ((t & 63) == 0) red[t >> 6] = v;
    __syncthreads();
    if (t == 0) atomicAdd(out, (red[0]+red[1])+(red[2]+red[3]));
}

__global__ void zero_out_kernel(float* __restrict__ out) { out[0] = 0.0f; }

// ---------------------------------------------------------------------------
extern "C" void kernel_launch(void* const* d_in, const int* in_sizes, int n_in,
                              void* d_out, int out_size, void* d_ws, size_t ws_size,
                              hipStream_t stream) {
    const float* mu   = (const float*)d_in[0];  // [DIM]
    const float* beta = (const float*)d_in[1];  // [P*DIM]
    const float* phi  = (const float*)d_in[2];  // [J]
    const float* X    = (const float*)d_in[3];  // [N,P]
    const float* Y    = (const float*)d_in[4];  // [N,J]
    float* out = (float*)d_out;
    float* ws  = (float*)d_ws;

    if (ws_size >= WS_TOTAL * sizeof(float)) {
        dim3 grid(G_CHUNKS, RGROUPS);
        prep_kernel<<<(J_GENES + BLOCK - 1) / BLOCK, BLOCK, 0, stream>>>(
            mu, beta, phi, ws, out);
        sums_kernel<<<grid, BLOCK, 0, stream>>>(X, Y, ws, ws);
        nb_kernel<<<grid, BLOCK, 0, stream>>>(X, Y, ws, out);
    } else {
        zero_out_kernel<<<1, 1, 0, stream>>>(out);
        nb_mono<<<N_SAMPLES, BLOCK, 0, stream>>>(mu, beta, phi, X, Y, out);
    }
}